// Round 7
// baseline (397.668 us; speedup 1.0000x reference)
//
#include <hip/hip_runtime.h>

#define NB 4
#define NN 65536
#define NK 16
#define NP (NB * NN)   // 262144 points
#define BN_EPS 1e-6f
#define LOG2E 1.44269504088896f

// ---- workspace layout (floats) ----
// enc moments over all (p,k), basis [cx,cy,cz,nx,ny,nz,1]:
//   [0..2] S_c(x16/pt)  [3..5] S_n  [6..11] M_cc upper  [12..20] M_cn 3x3  [21..26] M_nn upper
#define WS_ENC_M   0    // 27 floats
#define WS_SC_M    32   // S_f[8] @32, M_ff upper-tri 36 @40  (44 floats)
#define WS_S_Y2    96   // 8  pool1 conv sum
#define WS_SS_Y2   104  // 8
#define WS_S_Y4    112  // 16 pool2 conv sum
#define WS_SS_Y4   128  // 16 -> raw stats end at 144
// big buffers, channel-major [c][p] for coalesced access
#define WS_Y2      1024             // NP*8  floats (8 MB)
#define WS_Y4      (1024 + NP * 8)  // NP*16 floats (16 MB)

// entry+exit barriers REQUIRED (R5 lesson: LDS overlay races at high occupancy)
template <int NCH>
__device__ inline void blockReduceAtomic(float (&v)[NCH], float* __restrict__ dst) {
    __shared__ float red[4][NCH];
    const int lane = threadIdx.x & 63;
    const int wv = threadIdx.x >> 6;
    __syncthreads();
#pragma unroll
    for (int c = 0; c < NCH; c++) {
        float x = v[c];
#pragma unroll
        for (int off = 32; off > 0; off >>= 1) x += __shfl_xor(x, off, 64);
        if (lane == 0) red[wv][c] = x;
    }
    __syncthreads();
    for (int c = threadIdx.x; c < NCH; c += 256)
        atomicAdd(dst + c, red[0][c] + red[1][c] + red[2][c] + red[3][c]);
    __syncthreads();
}

// bn scale/shift for an lse conv channel from enc moments. w points at 10 weights.
__device__ inline void bn_from_enc(const float* __restrict__ M, const float* __restrict__ w,
                                   float b, float g, float bt, float& sc, float& sh) {
    float u[6];
    u[0] = w[0] + w[6]; u[1] = w[1] + w[7]; u[2] = w[2] + w[8];
    u[3] = w[3] - w[6]; u[4] = w[4] - w[7]; u[5] = w[5] - w[8];
    const float beta = b + w[9];
    float lin = 0.f;
#pragma unroll
    for (int i = 0; i < 6; i++) lin += u[i] * M[i];
    float quad = u[0] * u[0] * M[6] + 2.f * u[0] * u[1] * M[7] + 2.f * u[0] * u[2] * M[8]
               + u[1] * u[1] * M[9] + 2.f * u[1] * u[2] * M[10] + u[2] * u[2] * M[11];
#pragma unroll
    for (int i = 0; i < 3; i++)
#pragma unroll
        for (int j = 0; j < 3; j++) quad += 2.f * u[i] * u[3 + j] * M[12 + i * 3 + j];
    quad += u[3] * u[3] * M[21] + 2.f * u[3] * u[4] * M[22] + 2.f * u[3] * u[5] * M[23]
          + u[4] * u[4] * M[24] + 2.f * u[4] * u[5] * M[25] + u[5] * u[5] * M[26];
    const float cnt = (float)NP * (float)NK;
    const float sum = lin + cnt * beta;
    const float ss = quad + 2.f * beta * lin + cnt * beta * beta;
    const float m = sum / cnt, v = ss / cnt - m * m;
    sc = g * rsqrtf(v + BN_EPS);
    sh = bt - m * sc;
}

// ---------------- Kernel 1: enc moments, slot-parallel (8 slots/thread)
// every (p,k) slot adds the full outer-product terms of [c, n] -> no special cases
__global__ __launch_bounds__(256) void k_stats(
    const float* __restrict__ coords, const int* __restrict__ idx,
    float* __restrict__ ws) {
    const int t = blockIdx.x * 256 + threadIdx.x;   // t in [0, NP*2)
    const int p = t >> 1;
    const int b = p >> 16;
    const float cx = coords[3 * p], cy = coords[3 * p + 1], cz = coords[3 * p + 2];
    const float* cb = coords + b * NN * 3;
    const int4* ip = (const int4*)idx + t * 2;
    float acc[27] = {};
#pragma unroll
    for (int q = 0; q < 2; q++) {
        int4 v = ip[q];
        int jj[4] = {v.x, v.y, v.z, v.w};
        float nx[4], ny[4], nz[4];
#pragma unroll
        for (int e = 0; e < 4; e++) {
            nx[e] = cb[3 * jj[e]]; ny[e] = cb[3 * jj[e] + 1]; nz[e] = cb[3 * jj[e] + 2];
        }
#pragma unroll
        for (int e = 0; e < 4; e++) {
            acc[3] += nx[e]; acc[4] += ny[e]; acc[5] += nz[e];
            acc[12] += cx * nx[e]; acc[13] += cx * ny[e]; acc[14] += cx * nz[e];
            acc[15] += cy * nx[e]; acc[16] += cy * ny[e]; acc[17] += cy * nz[e];
            acc[18] += cz * nx[e]; acc[19] += cz * ny[e]; acc[20] += cz * nz[e];
            acc[21] += nx[e] * nx[e]; acc[22] += nx[e] * ny[e]; acc[23] += nx[e] * nz[e];
            acc[24] += ny[e] * ny[e]; acc[25] += ny[e] * nz[e]; acc[26] += nz[e] * nz[e];
        }
    }
    acc[0] = 8.f * cx; acc[1] = 8.f * cy; acc[2] = 8.f * cz;  // 8 slots x c per thread
    acc[6] = 8.f * cx * cx; acc[7] = 8.f * cx * cy; acc[8] = 8.f * cx * cz;
    acc[9] = 8.f * cy * cy; acc[10] = 8.f * cy * cz; acc[11] = 8.f * cz * cz;
    blockReduceAtomic<27>(acc, ws + WS_ENC_M);
}

// ---------------- Kernel 2: mlp1 + lse1 + pool1 -> y2, bn_p1 sums, shortcut feat moments
// 4 neighbors/thread, 4 lanes/point; block = 256 threads = 64 points
__global__ __launch_bounds__(256) void k_pool1(
    const float* __restrict__ coords, const float* __restrict__ feats,
    const int* __restrict__ idx,
    const float* __restrict__ w1, const float* __restrict__ b1,
    const float* __restrict__ lse1_w, const float* __restrict__ lse1_b,
    const float* __restrict__ lse1_g, const float* __restrict__ lse1_bt,
    const float* __restrict__ p1_sw, const float* __restrict__ p1_w,
    const float* __restrict__ p1_b, float* __restrict__ ws) {
    __shared__ float an[24], dc3[24], dcon[8], sws[64], pws[128], pbs[8], w1s[64], b1s[8];
    __shared__ float red[4][16];
    __shared__ float scst[64 * 44];
    const int tid = threadIdx.x;
    if (tid < 8) {
        const int c = tid;
        const float* w = lse1_w + c * 10;
        float sc, sh;
        bn_from_enc(ws + WS_ENC_M, w, lse1_b[c], lse1_g[c], lse1_bt[c], sc, sh);
#pragma unroll
        for (int i = 0; i < 3; i++) {
            an[c * 3 + i] = sc * (w[3 + i] - w[6 + i]);
            dc3[c * 3 + i] = sc * (w[i] + w[6 + i]);
        }
        dcon[c] = sc * (lse1_b[c] + w[9]) + sh;
        b1s[c] = b1[c]; pbs[c] = p1_b[c];
    }
    if (tid < 64) {
        w1s[tid] = w1[tid];
        sws[tid] = p1_sw[(tid >> 3) * 16 + (tid & 7)] * LOG2E;  // 8x8 block, exp2-folded
    }
    if (tid < 128) pws[tid] = p1_w[tid];
    __syncthreads();

    const int g = tid >> 2;          // point-local 0..63
    const int q = tid & 3;           // neighbor quarter
    const int p = blockIdx.x * 64 + g;
    const int b = p >> 16;
    const int n = p & (NN - 1);
    const float cx = coords[3 * p], cy = coords[3 * p + 1], cz = coords[3 * p + 2];
    const float* cb = coords + b * NN * 3;
    float d[8];
#pragma unroll
    for (int c = 0; c < 8; c++)
        d[c] = dc3[c * 3] * cx + dc3[c * 3 + 1] * cy + dc3[c * 3 + 2] * cz + dcon[c];
    const int4 v = ((const int4*)idx)[blockIdx.x * 256 + tid];  // coalesced
    int jj[4] = {v.x, v.y, v.z, v.w};
    float nx[4], ny[4], nz[4];
#pragma unroll
    for (int e = 0; e < 4; e++) {
        nx[e] = cb[3 * jj[e]]; ny[e] = cb[3 * jj[e] + 1]; nz[e] = cb[3 * jj[e] + 2];
    }
    float l[8] = {}, ac[8] = {};
#pragma unroll
    for (int e = 0; e < 4; e++) {
        float h[8];
#pragma unroll
        for (int c = 0; c < 8; c++) {
            float y = an[c * 3] * nx[e] + an[c * 3 + 1] * ny[e] + an[c * 3 + 2] * nz[e] + d[c];
            h[c] = y > 0.f ? y : 0.f;
        }
#pragma unroll
        for (int o = 0; o < 8; o++) {
            float s = 0.f;
#pragma unroll
            for (int i = 0; i < 8; i++) s += h[i] * sws[o * 8 + i];
            float e2 = exp2f(s);  // k-const part of score cancels in softmax
            l[o] += e2; ac[o] += e2 * h[o];
        }
    }
    // reduce softmax partials over the 4 lanes of this point
#pragma unroll
    for (int o = 0; o < 8; o++) {
        l[o] += __shfl_xor(l[o], 1, 64);  l[o] += __shfl_xor(l[o], 2, 64);
        ac[o] += __shfl_xor(ac[o], 1, 64); ac[o] += __shfl_xor(ac[o], 2, 64);
    }
    float agg[16];
#pragma unroll
    for (int o = 0; o < 8; o++) agg[o] = ac[o] * __builtin_amdgcn_rcpf(l[o]);
    // mlp1 (broadcast channels pool to themselves) — redundant across 4 lanes
    float f[8];
#pragma unroll
    for (int i = 0; i < 8; i++) f[i] = feats[(b * 8 + i) * NN + n];
#pragma unroll
    for (int j = 0; j < 8; j++) {
        float y = b1s[j];
#pragma unroll
        for (int i = 0; i < 8; i++) y += f[i] * w1s[j * 8 + i];
        agg[8 + j] = y > 0.f ? y : 0.2f * y;  // LeakyReLU(0.2)
    }
    // pool1 conv: this lane owns channels 2q, 2q+1
    float sy[2], syy[2];
#pragma unroll
    for (int t = 0; t < 2; t++) {
        const int c = 2 * q + t;
        float y = pbs[c];
#pragma unroll
        for (int o = 0; o < 16; o++) y += agg[o] * pws[c * 16 + o];
        ws[WS_Y2 + c * NP + p] = y;
        sy[t] = y; syy[t] = y * y;
    }
    // reduce stats over the 16 points of this wave (bits 2..5 of lane id)
#pragma unroll
    for (int off = 4; off < 64; off <<= 1) {
        sy[0] += __shfl_xor(sy[0], off, 64);  sy[1] += __shfl_xor(sy[1], off, 64);
        syy[0] += __shfl_xor(syy[0], off, 64); syy[1] += __shfl_xor(syy[1], off, 64);
    }
    // shortcut feature moments: owner lane q==0 per point stages into LDS
    if (q == 0) {
        float* s0 = scst + g * 44;
#pragma unroll
        for (int i = 0; i < 8; i++) s0[i] = f[i];
        int t2 = 8;
#pragma unroll
        for (int i = 0; i < 8; i++)
#pragma unroll
            for (int j2 = i; j2 < 8; j2++) s0[t2++] = f[i] * f[j2];
    }
    const int lane = tid & 63, wv = tid >> 6;
    if (lane < 4) {
        red[wv][2 * lane] = sy[0]; red[wv][2 * lane + 1] = sy[1];
        red[wv][8 + 2 * lane] = syy[0]; red[wv][8 + 2 * lane + 1] = syy[1];
    }
    __syncthreads();
    if (tid < 16)
        atomicAdd(ws + WS_S_Y2 + tid, red[0][tid] + red[1][tid] + red[2][tid] + red[3][tid]);
    if (tid < 44) {
        float s2 = 0.f;
        for (int g2 = 0; g2 < 64; g2++) s2 += scst[g2 * 44 + tid];
        atomicAdd(ws + WS_SC_M + tid, s2);
    }
}

// ---------------- Kernel 3: bn_p1+relu -> x2, lse2 + pool2 -> y4, bn_p2 sums
__global__ __launch_bounds__(256) void k_pool2(
    const float* __restrict__ coords, const int* __restrict__ idx,
    const float* __restrict__ lse2_w, const float* __restrict__ lse2_b,
    const float* __restrict__ lse2_g, const float* __restrict__ lse2_bt,
    const float* __restrict__ p1_g, const float* __restrict__ p1_bt,
    const float* __restrict__ p2_sw, const float* __restrict__ p2_w,
    const float* __restrict__ p2_b, float* __restrict__ ws) {
    __shared__ float an[24], dc3[24], dcon[8], p1sc[8], p1sh[8], sws[64], pws[256], pbs[16];
    __shared__ float red[4][32];
    const int tid = threadIdx.x;
    if (tid < 8) {
        const int c = tid;
        const float* w = lse2_w + c * 10;
        float sc, sh;
        bn_from_enc(ws + WS_ENC_M, w, lse2_b[c], lse2_g[c], lse2_bt[c], sc, sh);
#pragma unroll
        for (int i = 0; i < 3; i++) {
            an[c * 3 + i] = sc * (w[3 + i] - w[6 + i]);
            dc3[c * 3 + i] = sc * (w[i] + w[6 + i]);
        }
        dcon[c] = sc * (lse2_b[c] + w[9]) + sh;
    } else if (tid < 16) {  // bn_p1 from raw sums
        const int c = tid - 8;
        const float cP = 1.f / (float)NP;
        float m = ws[WS_S_Y2 + c] * cP, vv = ws[WS_SS_Y2 + c] * cP - m * m;
        float sc = p1_g[c] * rsqrtf(vv + BN_EPS);
        p1sc[c] = sc; p1sh[c] = p1_bt[c] - m * sc;
    }
    if (tid < 64) sws[tid] = p2_sw[(tid >> 3) * 16 + (tid & 7)] * LOG2E;
    if (tid < 256) pws[tid] = p2_w[tid];
    if (tid < 16) pbs[tid] = p2_b[tid];
    __syncthreads();

    const int g = tid >> 2;
    const int q = tid & 3;
    const int p = blockIdx.x * 64 + g;
    const int b = p >> 16;
    const float cx = coords[3 * p], cy = coords[3 * p + 1], cz = coords[3 * p + 2];
    const float* cb = coords + b * NN * 3;
    float d[8];
#pragma unroll
    for (int c = 0; c < 8; c++)
        d[c] = dc3[c * 3] * cx + dc3[c * 3 + 1] * cy + dc3[c * 3 + 2] * cz + dcon[c];
    const int4 v = ((const int4*)idx)[blockIdx.x * 256 + tid];
    int jj[4] = {v.x, v.y, v.z, v.w};
    float nx[4], ny[4], nz[4];
#pragma unroll
    for (int e = 0; e < 4; e++) {
        nx[e] = cb[3 * jj[e]]; ny[e] = cb[3 * jj[e] + 1]; nz[e] = cb[3 * jj[e] + 2];
    }
    float l[8] = {}, ac[8] = {};
#pragma unroll
    for (int e = 0; e < 4; e++) {
        float h[8];
#pragma unroll
        for (int c = 0; c < 8; c++) {
            float y = an[c * 3] * nx[e] + an[c * 3 + 1] * ny[e] + an[c * 3 + 2] * nz[e] + d[c];
            h[c] = y > 0.f ? y : 0.f;
        }
#pragma unroll
        for (int o = 0; o < 8; o++) {
            float s = 0.f;
#pragma unroll
            for (int i = 0; i < 8; i++) s += h[i] * sws[o * 8 + i];
            float e2 = exp2f(s);
            l[o] += e2; ac[o] += e2 * h[o];
        }
    }
#pragma unroll
    for (int o = 0; o < 8; o++) {
        l[o] += __shfl_xor(l[o], 1, 64);  l[o] += __shfl_xor(l[o], 2, 64);
        ac[o] += __shfl_xor(ac[o], 1, 64); ac[o] += __shfl_xor(ac[o], 2, 64);
    }
    float agg[16];
#pragma unroll
    for (int o = 0; o < 8; o++) agg[o] = ac[o] * __builtin_amdgcn_rcpf(l[o]);
#pragma unroll
    for (int c = 0; c < 8; c++) {
        float y = ws[WS_Y2 + c * NP + p] * p1sc[c] + p1sh[c];
        agg[8 + c] = y > 0.f ? y : 0.f;
    }
    // pool2 conv: this lane owns channels 4q..4q+3
    float sy[4], syy[4];
#pragma unroll
    for (int t = 0; t < 4; t++) {
        const int c = 4 * q + t;
        float y = pbs[c];
#pragma unroll
        for (int o = 0; o < 16; o++) y += agg[o] * pws[c * 16 + o];
        ws[WS_Y4 + c * NP + p] = y;
        sy[t] = y; syy[t] = y * y;
    }
#pragma unroll
    for (int off = 4; off < 64; off <<= 1) {
#pragma unroll
        for (int t = 0; t < 4; t++) {
            sy[t] += __shfl_xor(sy[t], off, 64);
            syy[t] += __shfl_xor(syy[t], off, 64);
        }
    }
    const int lane = tid & 63, wv = tid >> 6;
    if (lane < 4) {
#pragma unroll
        for (int t = 0; t < 4; t++) {
            red[wv][4 * lane + t] = sy[t];
            red[wv][16 + 4 * lane + t] = syy[t];
        }
    }
    __syncthreads();
    if (tid < 32)
        atomicAdd(ws + WS_S_Y4 + tid, red[0][tid] + red[1][tid] + red[2][tid] + red[3][tid]);
}

// ---------------- Kernel 4: x4 = relu(bn(y4)); out = leaky(w2@x4 + b2 + bn(sc_w@feats))
__global__ __launch_bounds__(256) void k_final(
    const float* __restrict__ feats, const float* __restrict__ w2,
    const float* __restrict__ b2, const float* __restrict__ sc_w,
    const float* __restrict__ sc_b, const float* __restrict__ p2_g,
    const float* __restrict__ p2_bt, const float* __restrict__ sc_g,
    const float* __restrict__ sc_bt, const float* __restrict__ ws,
    float* __restrict__ out) {
    __shared__ float w2s[512], b2s[32], scws[256], scbs[32],
        p2sc[16], p2sh[16], scsc[32], scsh[32];
    const int tid = threadIdx.x;
    for (int i = tid; i < 512; i += 256) w2s[i] = w2[i];
    if (tid < 256) scws[tid] = sc_w[tid];
    if (tid < 32) {
        b2s[tid] = b2[tid]; scbs[tid] = sc_b[tid];
        const int c = tid;
        const float* w = sc_w + c * 8;
        const float* S = ws + WS_SC_M;
        float lin = 0.f;
#pragma unroll
        for (int i = 0; i < 8; i++) lin += w[i] * S[i];
        float quad = 0.f;
        int t2 = 0;
#pragma unroll
        for (int i = 0; i < 8; i++)
#pragma unroll
            for (int j = i; j < 8; j++) {
                const float mm = S[8 + t2++];
                quad += (i == j ? 1.f : 2.f) * w[i] * w[j] * mm;
            }
        const float cnt = (float)NP;
        const float bb = sc_b[c];
        const float sum = lin + cnt * bb;
        const float ss = quad + 2.f * bb * lin + cnt * bb * bb;
        const float m = sum / cnt, vv = ss / cnt - m * m;
        const float sc = sc_g[c] * rsqrtf(vv + BN_EPS);
        scsc[c] = sc; scsh[c] = sc_bt[c] - m * sc;
    }
    if (tid < 16) {
        const int c = tid;
        const float cP = 1.f / (float)NP;
        float m = ws[WS_S_Y4 + c] * cP, vv = ws[WS_SS_Y4 + c] * cP - m * m;
        float sc = p2_g[c] * rsqrtf(vv + BN_EPS);
        p2sc[c] = sc; p2sh[c] = p2_bt[c] - m * sc;
    }
    __syncthreads();

    const int p = blockIdx.x * 256 + tid;
    const int b = p >> 16;
    const int n = p & (NN - 1);
    float x4[16];
#pragma unroll
    for (int c = 0; c < 16; c++) {
        float y = ws[WS_Y4 + c * NP + p] * p2sc[c] + p2sh[c];
        x4[c] = y > 0.f ? y : 0.f;
    }
    float f[8];
#pragma unroll
    for (int i = 0; i < 8; i++) f[i] = feats[(b * 8 + i) * NN + n];
#pragma unroll
    for (int c = 0; c < 32; c++) {
        float s = scbs[c];
#pragma unroll
        for (int i = 0; i < 8; i++) s += f[i] * scws[c * 8 + i];
        s = s * scsc[c] + scsh[c];  // bn, no activation
        float m = b2s[c];
#pragma unroll
        for (int o = 0; o < 16; o++) m += x4[o] * w2s[c * 16 + o];
        float vv = m + s;
        out[(b * 32 + c) * NN + n] = vv > 0.f ? vv : 0.01f * vv;  // LeakyReLU(0.01)
    }
}

extern "C" void kernel_launch(void* const* d_in, const int* in_sizes, int n_in,
                              void* d_out, int out_size, void* d_ws, size_t ws_size,
                              hipStream_t stream) {
    (void)in_sizes; (void)n_in; (void)out_size; (void)ws_size;
    const float* coords = (const float*)d_in[0];
    const float* features = (const float*)d_in[1];
    const int* idx = (const int*)d_in[2];
    const float* w1 = (const float*)d_in[3];
    const float* b1 = (const float*)d_in[4];
    const float* lse1_w = (const float*)d_in[5];
    const float* lse1_b = (const float*)d_in[6];
    const float* lse1_g = (const float*)d_in[7];
    const float* lse1_bt = (const float*)d_in[8];
    const float* p1_sw = (const float*)d_in[9];
    const float* p1_w = (const float*)d_in[10];
    const float* p1_b = (const float*)d_in[11];
    const float* p1_g = (const float*)d_in[12];
    const float* p1_bt = (const float*)d_in[13];
    const float* lse2_w = (const float*)d_in[14];
    const float* lse2_b = (const float*)d_in[15];
    const float* lse2_g = (const float*)d_in[16];
    const float* lse2_bt = (const float*)d_in[17];
    const float* p2_sw = (const float*)d_in[18];
    const float* p2_w = (const float*)d_in[19];
    const float* p2_b = (const float*)d_in[20];
    const float* p2_g = (const float*)d_in[21];
    const float* p2_bt = (const float*)d_in[22];
    const float* w2 = (const float*)d_in[23];
    const float* b2 = (const float*)d_in[24];
    const float* sc_w = (const float*)d_in[25];
    const float* sc_b = (const float*)d_in[26];
    const float* sc_g = (const float*)d_in[27];
    const float* sc_bt = (const float*)d_in[28];
    float* ws = (float*)d_ws;
    float* out = (float*)d_out;

    hipMemsetAsync(ws, 0, 144 * sizeof(float), stream);
    k_stats<<<NP * 2 / 256, 256, 0, stream>>>(coords, idx, ws);
    k_pool1<<<NP / 64, 256, 0, stream>>>(coords, features, idx, w1, b1, lse1_w, lse1_b,
                                         lse1_g, lse1_bt, p1_sw, p1_w, p1_b, ws);
    k_pool2<<<NP / 64, 256, 0, stream>>>(coords, idx, lse2_w, lse2_b, lse2_g, lse2_bt,
                                         p1_g, p1_bt, p2_sw, p2_w, p2_b, ws);
    k_final<<<NP / 256, 256, 0, stream>>>(features, w2, b2, sc_w, sc_b, p2_g, p2_bt,
                                          sc_g, sc_bt, ws, out);
}

// Round 8
// 363.860 us; speedup vs baseline: 1.0929x; 1.0929x over previous
//
#include <hip/hip_runtime.h>

#define NB 4
#define NN 65536
#define NK 16
#define NP (NB * NN)   // 262144 points
#define BN_EPS 1e-6f
#define LOG2E 1.44269504088896f

// ---- workspace layout (floats) ----
// enc moments over all (p,k), basis [cx,cy,cz,nx,ny,nz,1]:
//   [0..2] S_c(x16/pt)  [3..5] S_n  [6..11] M_cc upper  [12..20] M_cn 3x3  [21..26] M_nn upper
#define WS_ENC_M   0    // 27 floats
#define WS_SC_M    32   // S_f[8] @32, M_ff upper-tri 36 @40  (44 floats)
#define WS_S_Y2    96   // 8  pool1 conv sum
#define WS_SS_Y2   104  // 8
#define WS_S_Y4    112  // 16 pool2 conv sum
#define WS_SS_Y4   128  // 16 -> raw stats end at 144
// big buffers, channel-major [c][p] for coalesced access
#define WS_Y2      1024               // NP*8  floats (8 MB)
#define WS_Y4      (1024 + NP * 8)    // NP*16 floats (16 MB)
#define WS_C4      (1024 + NP * 24)   // NP*4  floats (4 MB) packed coords float4

// entry+exit barriers REQUIRED (R5 lesson: LDS overlay races at high occupancy)
template <int NCH>
__device__ inline void blockReduceAtomic(float (&v)[NCH], float* __restrict__ dst) {
    __shared__ float red[4][NCH];
    const int lane = threadIdx.x & 63;
    const int wv = threadIdx.x >> 6;
    __syncthreads();
#pragma unroll
    for (int c = 0; c < NCH; c++) {
        float x = v[c];
#pragma unroll
        for (int off = 32; off > 0; off >>= 1) x += __shfl_xor(x, off, 64);
        if (lane == 0) red[wv][c] = x;
    }
    __syncthreads();
    for (int c = threadIdx.x; c < NCH; c += 256)
        atomicAdd(dst + c, red[0][c] + red[1][c] + red[2][c] + red[3][c]);
    __syncthreads();
}

// bn scale/shift for an lse conv channel from enc moments. w points at 10 weights.
__device__ inline void bn_from_enc(const float* __restrict__ M, const float* __restrict__ w,
                                   float b, float g, float bt, float& sc, float& sh) {
    float u[6];
    u[0] = w[0] + w[6]; u[1] = w[1] + w[7]; u[2] = w[2] + w[8];
    u[3] = w[3] - w[6]; u[4] = w[4] - w[7]; u[5] = w[5] - w[8];
    const float beta = b + w[9];
    float lin = 0.f;
#pragma unroll
    for (int i = 0; i < 6; i++) lin += u[i] * M[i];
    float quad = u[0] * u[0] * M[6] + 2.f * u[0] * u[1] * M[7] + 2.f * u[0] * u[2] * M[8]
               + u[1] * u[1] * M[9] + 2.f * u[1] * u[2] * M[10] + u[2] * u[2] * M[11];
#pragma unroll
    for (int i = 0; i < 3; i++)
#pragma unroll
        for (int j = 0; j < 3; j++) quad += 2.f * u[i] * u[3 + j] * M[12 + i * 3 + j];
    quad += u[3] * u[3] * M[21] + 2.f * u[3] * u[4] * M[22] + 2.f * u[3] * u[5] * M[23]
          + u[4] * u[4] * M[24] + 2.f * u[4] * u[5] * M[25] + u[5] * u[5] * M[26];
    const float cnt = (float)NP * (float)NK;
    const float sum = lin + cnt * beta;
    const float ss = quad + 2.f * beta * lin + cnt * beta * beta;
    const float m = sum / cnt, v = ss / cnt - m * m;
    sc = g * rsqrtf(v + BN_EPS);
    sh = bt - m * sc;
}

// ---------------- Kernel 0: pack coords -> float4 in ws (coalesced both ways)
__global__ __launch_bounds__(256) void k_prep(
    const float* __restrict__ coords, float4* __restrict__ c4) {
    const int p = blockIdx.x * 256 + threadIdx.x;
    c4[p] = make_float4(coords[3 * p], coords[3 * p + 1], coords[3 * p + 2], 0.f);
}

// ---------------- Kernel 1: enc moments + shortcut feat moments (float4 gathers)
__global__ __launch_bounds__(256) void k_stats(
    const float4* __restrict__ c4, const float* __restrict__ feats,
    const int* __restrict__ idx, float* __restrict__ ws) {
    const int tid = threadIdx.x;
    const int p = blockIdx.x * 256 + tid;
    const int b = p >> 16;
    const int n = p & (NN - 1);

    // shortcut feature moments first (retire registers before nbr loop)
    {
        float accf[44];
        float f[8];
#pragma unroll
        for (int i = 0; i < 8; i++) f[i] = feats[(b * 8 + i) * NN + n];
#pragma unroll
        for (int i = 0; i < 8; i++) accf[i] = f[i];
        int t2 = 8;
#pragma unroll
        for (int i = 0; i < 8; i++)
#pragma unroll
            for (int j = i; j < 8; j++) accf[t2++] = f[i] * f[j];
        blockReduceAtomic<44>(accf, ws + WS_SC_M);
    }

    const int boff = b << 16;
    const float4 me = c4[p];
    const int4* ip = (const int4*)idx + p * 4;
    float sn0 = 0.f, sn1 = 0.f, sn2 = 0.f;
    float m00 = 0.f, m01 = 0.f, m02 = 0.f, m11 = 0.f, m12 = 0.f, m22 = 0.f;
#pragma unroll
    for (int q = 0; q < 4; q++) {
        int4 v = ip[q];
        int jj[4] = {v.x, v.y, v.z, v.w};
#pragma unroll
        for (int e = 0; e < 4; e++) {
            const float4 nn = c4[boff + jj[e]];
            sn0 += nn.x; sn1 += nn.y; sn2 += nn.z;
            m00 += nn.x * nn.x; m01 += nn.x * nn.y; m02 += nn.x * nn.z;
            m11 += nn.y * nn.y; m12 += nn.y * nn.z; m22 += nn.z * nn.z;
        }
    }
    float acc[27];
    acc[0] = 16.f * me.x; acc[1] = 16.f * me.y; acc[2] = 16.f * me.z;
    acc[3] = sn0; acc[4] = sn1; acc[5] = sn2;
    acc[6] = 16.f * me.x * me.x; acc[7] = 16.f * me.x * me.y; acc[8] = 16.f * me.x * me.z;
    acc[9] = 16.f * me.y * me.y; acc[10] = 16.f * me.y * me.z; acc[11] = 16.f * me.z * me.z;
    acc[12] = me.x * sn0; acc[13] = me.x * sn1; acc[14] = me.x * sn2;
    acc[15] = me.y * sn0; acc[16] = me.y * sn1; acc[17] = me.y * sn2;
    acc[18] = me.z * sn0; acc[19] = me.z * sn1; acc[20] = me.z * sn2;
    acc[21] = m00; acc[22] = m01; acc[23] = m02;
    acc[24] = m11; acc[25] = m12; acc[26] = m22;
    blockReduceAtomic<27>(acc, ws + WS_ENC_M);
}

// ---------------- Kernel 2: mlp1 + lse1 + pool1 -> y2 (pre-BN), bn_p1 raw sums
// point-per-thread (R6 structure), float4 gathers
__global__ __launch_bounds__(256) void k_pool1(
    const float4* __restrict__ c4, const float* __restrict__ feats,
    const int* __restrict__ idx,
    const float* __restrict__ w1, const float* __restrict__ b1,
    const float* __restrict__ lse1_w, const float* __restrict__ lse1_b,
    const float* __restrict__ lse1_g, const float* __restrict__ lse1_bt,
    const float* __restrict__ p1_sw, const float* __restrict__ p1_w,
    const float* __restrict__ p1_b, float* __restrict__ ws) {
    __shared__ float an[24], dc3[24], dcon[8], sws[64], pws[128], pbs[8], w1s[64], b1s[8];
    const int tid = threadIdx.x;
    if (tid < 8) {
        const int c = tid;
        const float* w = lse1_w + c * 10;
        float sc, sh;
        bn_from_enc(ws + WS_ENC_M, w, lse1_b[c], lse1_g[c], lse1_bt[c], sc, sh);
#pragma unroll
        for (int i = 0; i < 3; i++) {
            an[c * 3 + i] = sc * (w[3 + i] - w[6 + i]);
            dc3[c * 3 + i] = sc * (w[i] + w[6 + i]);
        }
        dcon[c] = sc * (lse1_b[c] + w[9]) + sh;
        b1s[c] = b1[c]; pbs[c] = p1_b[c];
    }
    if (tid < 64) {
        w1s[tid] = w1[tid];
        sws[tid] = p1_sw[(tid >> 3) * 16 + (tid & 7)] * LOG2E;  // 8x8 block, exp2-folded
    }
    if (tid < 128) pws[tid] = p1_w[tid];
    __syncthreads();

    const int p = blockIdx.x * 256 + tid;
    const int b = p >> 16;
    const int n = p & (NN - 1);
    const int boff = b << 16;
    const float4 me = c4[p];
    float d[8];
#pragma unroll
    for (int c = 0; c < 8; c++)
        d[c] = dc3[c * 3] * me.x + dc3[c * 3 + 1] * me.y + dc3[c * 3 + 2] * me.z + dcon[c];
    const int4* ip = (const int4*)idx + p * 4;
    float l[8] = {}, ac[8] = {};
#pragma unroll
    for (int q = 0; q < 4; q++) {
        int4 v = ip[q];
        int jj[4] = {v.x, v.y, v.z, v.w};
#pragma unroll
        for (int e = 0; e < 4; e++) {
            const float4 nn = c4[boff + jj[e]];
            float h[8];
#pragma unroll
            for (int c = 0; c < 8; c++) {
                float y = an[c * 3] * nn.x + an[c * 3 + 1] * nn.y + an[c * 3 + 2] * nn.z + d[c];
                h[c] = y > 0.f ? y : 0.f;
            }
#pragma unroll
            for (int o = 0; o < 8; o++) {
                float s = 0.f;
#pragma unroll
                for (int i = 0; i < 8; i++) s += h[i] * sws[o * 8 + i];
                float e2 = exp2f(s);  // k-const part of score cancels in softmax
                l[o] += e2; ac[o] += e2 * h[o];
            }
        }
    }
    // epilogue: mlp1 (broadcast channels pool to themselves), pool1 conv
    float f[8];
#pragma unroll
    for (int i = 0; i < 8; i++) f[i] = feats[(b * 8 + i) * NN + n];
    float agg[16];
#pragma unroll
    for (int o = 0; o < 8; o++) agg[o] = ac[o] / l[o];
#pragma unroll
    for (int jq = 0; jq < 8; jq++) {
        float y = b1s[jq];
#pragma unroll
        for (int i = 0; i < 8; i++) y += f[i] * w1s[jq * 8 + i];
        agg[8 + jq] = y > 0.f ? y : 0.2f * y;  // LeakyReLU(0.2)
    }
    float st[16];
#pragma unroll
    for (int c = 0; c < 8; c++) {
        float y = pbs[c];
#pragma unroll
        for (int o = 0; o < 16; o++) y += agg[o] * pws[c * 16 + o];
        ws[WS_Y2 + c * NP + p] = y;
        st[c] = y; st[8 + c] = y * y;
    }
    blockReduceAtomic<16>(st, ws + WS_S_Y2);
}

// ---------------- Kernel 3: bn_p1+relu -> x2, lse2 + pool2 -> y4 (pre-BN), bn_p2 raw sums
__global__ __launch_bounds__(256) void k_pool2(
    const float4* __restrict__ c4, const int* __restrict__ idx,
    const float* __restrict__ lse2_w, const float* __restrict__ lse2_b,
    const float* __restrict__ lse2_g, const float* __restrict__ lse2_bt,
    const float* __restrict__ p1_g, const float* __restrict__ p1_bt,
    const float* __restrict__ p2_sw, const float* __restrict__ p2_w,
    const float* __restrict__ p2_b, float* __restrict__ ws) {
    __shared__ float an[24], dc3[24], dcon[8], p1sc[8], p1sh[8], sws[64], pws[256], pbs[16];
    const int tid = threadIdx.x;
    if (tid < 8) {
        const int c = tid;
        const float* w = lse2_w + c * 10;
        float sc, sh;
        bn_from_enc(ws + WS_ENC_M, w, lse2_b[c], lse2_g[c], lse2_bt[c], sc, sh);
#pragma unroll
        for (int i = 0; i < 3; i++) {
            an[c * 3 + i] = sc * (w[3 + i] - w[6 + i]);
            dc3[c * 3 + i] = sc * (w[i] + w[6 + i]);
        }
        dcon[c] = sc * (lse2_b[c] + w[9]) + sh;
    } else if (tid < 16) {  // bn_p1 from raw sums
        const int c = tid - 8;
        const float cP = 1.f / (float)NP;
        float m = ws[WS_S_Y2 + c] * cP, vv = ws[WS_SS_Y2 + c] * cP - m * m;
        float sc = p1_g[c] * rsqrtf(vv + BN_EPS);
        p1sc[c] = sc; p1sh[c] = p1_bt[c] - m * sc;
    }
    if (tid < 64) sws[tid] = p2_sw[(tid >> 3) * 16 + (tid & 7)] * LOG2E;
    if (tid < 256) pws[tid] = p2_w[tid];
    if (tid < 16) pbs[tid] = p2_b[tid];
    __syncthreads();

    const int p = blockIdx.x * 256 + tid;
    const int boff = (p >> 16) << 16;
    const float4 me = c4[p];
    float d[8];
#pragma unroll
    for (int c = 0; c < 8; c++)
        d[c] = dc3[c * 3] * me.x + dc3[c * 3 + 1] * me.y + dc3[c * 3 + 2] * me.z + dcon[c];
    const int4* ip = (const int4*)idx + p * 4;
    float l[8] = {}, ac[8] = {};
#pragma unroll
    for (int q = 0; q < 4; q++) {
        int4 v = ip[q];
        int jj[4] = {v.x, v.y, v.z, v.w};
#pragma unroll
        for (int e = 0; e < 4; e++) {
            const float4 nn = c4[boff + jj[e]];
            float h[8];
#pragma unroll
            for (int c = 0; c < 8; c++) {
                float y = an[c * 3] * nn.x + an[c * 3 + 1] * nn.y + an[c * 3 + 2] * nn.z + d[c];
                h[c] = y > 0.f ? y : 0.f;
            }
#pragma unroll
            for (int o = 0; o < 8; o++) {
                float s = 0.f;
#pragma unroll
                for (int i = 0; i < 8; i++) s += h[i] * sws[o * 8 + i];
                float e2 = exp2f(s);
                l[o] += e2; ac[o] += e2 * h[o];
            }
        }
    }
    float agg[16];
#pragma unroll
    for (int o = 0; o < 8; o++) agg[o] = ac[o] / l[o];
#pragma unroll
    for (int c = 0; c < 8; c++) {
        float y = ws[WS_Y2 + c * NP + p] * p1sc[c] + p1sh[c];
        agg[8 + c] = y > 0.f ? y : 0.f;
    }
    float st[32];
#pragma unroll
    for (int c = 0; c < 16; c++) {
        float y = pbs[c];
#pragma unroll
        for (int o = 0; o < 16; o++) y += agg[o] * pws[c * 16 + o];
        ws[WS_Y4 + c * NP + p] = y;
        st[c] = y; st[16 + c] = y * y;
    }
    blockReduceAtomic<32>(st, ws + WS_S_Y4);
}

// ---------------- Kernel 4: x4 = relu(bn(y4)); out = leaky(w2@x4 + b2 + bn(sc_w@feats))
__global__ __launch_bounds__(256) void k_final(
    const float* __restrict__ feats, const float* __restrict__ w2,
    const float* __restrict__ b2, const float* __restrict__ sc_w,
    const float* __restrict__ sc_b, const float* __restrict__ p2_g,
    const float* __restrict__ p2_bt, const float* __restrict__ sc_g,
    const float* __restrict__ sc_bt, const float* __restrict__ ws,
    float* __restrict__ out) {
    __shared__ float w2s[512], b2s[32], scws[256], scbs[32],
        p2sc[16], p2sh[16], scsc[32], scsh[32];
    const int tid = threadIdx.x;
    for (int i = tid; i < 512; i += 256) w2s[i] = w2[i];
    if (tid < 256) scws[tid] = sc_w[tid];
    if (tid < 32) {
        b2s[tid] = b2[tid]; scbs[tid] = sc_b[tid];
        const int c = tid;
        const float* w = sc_w + c * 8;
        const float* S = ws + WS_SC_M;
        float lin = 0.f;
#pragma unroll
        for (int i = 0; i < 8; i++) lin += w[i] * S[i];
        float quad = 0.f;
        int t2 = 0;
#pragma unroll
        for (int i = 0; i < 8; i++)
#pragma unroll
            for (int j = i; j < 8; j++) {
                const float mm = S[8 + t2++];
                quad += (i == j ? 1.f : 2.f) * w[i] * w[j] * mm;
            }
        const float cnt = (float)NP;
        const float bb = sc_b[c];
        const float sum = lin + cnt * bb;
        const float ss = quad + 2.f * bb * lin + cnt * bb * bb;
        const float m = sum / cnt, vv = ss / cnt - m * m;
        const float sc = sc_g[c] * rsqrtf(vv + BN_EPS);
        scsc[c] = sc; scsh[c] = sc_bt[c] - m * sc;
    }
    if (tid < 16) {
        const int c = tid;
        const float cP = 1.f / (float)NP;
        float m = ws[WS_S_Y4 + c] * cP, vv = ws[WS_SS_Y4 + c] * cP - m * m;
        float sc = p2_g[c] * rsqrtf(vv + BN_EPS);
        p2sc[c] = sc; p2sh[c] = p2_bt[c] - m * sc;
    }
    __syncthreads();

    const int p = blockIdx.x * 256 + tid;
    const int b = p >> 16;
    const int n = p & (NN - 1);
    float x4[16];
#pragma unroll
    for (int c = 0; c < 16; c++) {
        float y = ws[WS_Y4 + c * NP + p] * p2sc[c] + p2sh[c];
        x4[c] = y > 0.f ? y : 0.f;
    }
    float f[8];
#pragma unroll
    for (int i = 0; i < 8; i++) f[i] = feats[(b * 8 + i) * NN + n];
#pragma unroll
    for (int c = 0; c < 32; c++) {
        float s = scbs[c];
#pragma unroll
        for (int i = 0; i < 8; i++) s += f[i] * scws[c * 8 + i];
        s = s * scsc[c] + scsh[c];  // bn, no activation
        float m = b2s[c];
#pragma unroll
        for (int o = 0; o < 16; o++) m += x4[o] * w2s[c * 16 + o];
        float vv = m + s;
        out[(b * 32 + c) * NN + n] = vv > 0.f ? vv : 0.01f * vv;  // LeakyReLU(0.01)
    }
}

extern "C" void kernel_launch(void* const* d_in, const int* in_sizes, int n_in,
                              void* d_out, int out_size, void* d_ws, size_t ws_size,
                              hipStream_t stream) {
    (void)in_sizes; (void)n_in; (void)out_size; (void)ws_size;
    const float* coords = (const float*)d_in[0];
    const float* features = (const float*)d_in[1];
    const int* idx = (const int*)d_in[2];
    const float* w1 = (const float*)d_in[3];
    const float* b1 = (const float*)d_in[4];
    const float* lse1_w = (const float*)d_in[5];
    const float* lse1_b = (const float*)d_in[6];
    const float* lse1_g = (const float*)d_in[7];
    const float* lse1_bt = (const float*)d_in[8];
    const float* p1_sw = (const float*)d_in[9];
    const float* p1_w = (const float*)d_in[10];
    const float* p1_b = (const float*)d_in[11];
    const float* p1_g = (const float*)d_in[12];
    const float* p1_bt = (const float*)d_in[13];
    const float* lse2_w = (const float*)d_in[14];
    const float* lse2_b = (const float*)d_in[15];
    const float* lse2_g = (const float*)d_in[16];
    const float* lse2_bt = (const float*)d_in[17];
    const float* p2_sw = (const float*)d_in[18];
    const float* p2_w = (const float*)d_in[19];
    const float* p2_b = (const float*)d_in[20];
    const float* p2_g = (const float*)d_in[21];
    const float* p2_bt = (const float*)d_in[22];
    const float* w2 = (const float*)d_in[23];
    const float* b2 = (const float*)d_in[24];
    const float* sc_w = (const float*)d_in[25];
    const float* sc_b = (const float*)d_in[26];
    const float* sc_g = (const float*)d_in[27];
    const float* sc_bt = (const float*)d_in[28];
    float* ws = (float*)d_ws;
    float* out = (float*)d_out;
    float4* c4 = (float4*)(ws + WS_C4);

    const int NBLK = NP / 256;
    hipMemsetAsync(ws, 0, 144 * sizeof(float), stream);
    k_prep<<<NBLK, 256, 0, stream>>>(coords, c4);
    k_stats<<<NBLK, 256, 0, stream>>>(c4, features, idx, ws);
    k_pool1<<<NBLK, 256, 0, stream>>>(c4, features, idx, w1, b1, lse1_w, lse1_b,
                                      lse1_g, lse1_bt, p1_sw, p1_w, p1_b, ws);
    k_pool2<<<NBLK, 256, 0, stream>>>(c4, idx, lse2_w, lse2_b, lse2_g, lse2_bt,
                                      p1_g, p1_bt, p2_sw, p2_w, p2_b, ws);
    k_final<<<NBLK, 256, 0, stream>>>(features, w2, b2, sc_w, sc_b, p2_g, p2_bt,
                                      sc_g, sc_bt, ws, out);
}

// Round 9
// 349.452 us; speedup vs baseline: 1.1380x; 1.0412x over previous
//
#include <hip/hip_runtime.h>

#define NB 4
#define NN 65536
#define NK 16
#define NP (NB * NN)   // 262144 points
#define BN_EPS 1e-6f
#define LOG2E 1.44269504088896f

// ---- workspace layout (floats) ----
#define WS_ENC_M   0    // 27 floats: enc moments basis [c,n,1]
#define WS_SC_M    32   // S_f[8] @32, M_ff upper-tri 36 @40  (44 floats)
#define WS_S_Y2    96   // 8  pool1 conv sum
#define WS_SS_Y2   104  // 8
#define WS_S_Y4    112  // 16 pool2 conv sum
#define WS_SS_Y4   128  // 16 -> raw stats end at 144
#define WS_Y2      1024               // NP*8  floats (8 MB), channel-major
#define WS_Y4      (1024 + NP * 8)    // NP*16 floats (16 MB)
#define WS_C4      (1024 + NP * 24)   // NP*4  floats (4 MB) packed coords float4

// entry+exit barriers REQUIRED (R5 lesson: LDS overlay races at high occupancy)
template <int NCH>
__device__ inline void blockReduceAtomic(float (&v)[NCH], float* __restrict__ dst) {
    __shared__ float red[4][NCH];
    const int lane = threadIdx.x & 63;
    const int wv = threadIdx.x >> 6;
    __syncthreads();
#pragma unroll
    for (int c = 0; c < NCH; c++) {
        float x = v[c];
#pragma unroll
        for (int off = 32; off > 0; off >>= 1) x += __shfl_xor(x, off, 64);
        if (lane == 0) red[wv][c] = x;
    }
    __syncthreads();
    for (int c = threadIdx.x; c < NCH; c += 256)
        atomicAdd(dst + c, red[0][c] + red[1][c] + red[2][c] + red[3][c]);
    __syncthreads();
}

// bn scale/shift for an lse conv channel from enc moments. w points at 10 weights.
__device__ inline void bn_from_enc(const float* __restrict__ M, const float* __restrict__ w,
                                   float b, float g, float bt, float& sc, float& sh) {
    float u[6];
    u[0] = w[0] + w[6]; u[1] = w[1] + w[7]; u[2] = w[2] + w[8];
    u[3] = w[3] - w[6]; u[4] = w[4] - w[7]; u[5] = w[5] - w[8];
    const float beta = b + w[9];
    float lin = 0.f;
#pragma unroll
    for (int i = 0; i < 6; i++) lin += u[i] * M[i];
    float quad = u[0] * u[0] * M[6] + 2.f * u[0] * u[1] * M[7] + 2.f * u[0] * u[2] * M[8]
               + u[1] * u[1] * M[9] + 2.f * u[1] * u[2] * M[10] + u[2] * u[2] * M[11];
#pragma unroll
    for (int i = 0; i < 3; i++)
#pragma unroll
        for (int j = 0; j < 3; j++) quad += 2.f * u[i] * u[3 + j] * M[12 + i * 3 + j];
    quad += u[3] * u[3] * M[21] + 2.f * u[3] * u[4] * M[22] + 2.f * u[3] * u[5] * M[23]
          + u[4] * u[4] * M[24] + 2.f * u[4] * u[5] * M[25] + u[5] * u[5] * M[26];
    const float cnt = (float)NP * (float)NK;
    const float sum = lin + cnt * beta;
    const float ss = quad + 2.f * beta * lin + cnt * beta * beta;
    const float m = sum / cnt, v = ss / cnt - m * m;
    sc = g * rsqrtf(v + BN_EPS);
    sh = bt - m * sc;
}

// ---------------- Kernel 0: pack coords -> float4 in ws (coalesced both ways)
__global__ __launch_bounds__(256) void k_prep(
    const float* __restrict__ coords, float4* __restrict__ c4) {
    const int p = blockIdx.x * 256 + threadIdx.x;
    c4[p] = make_float4(coords[3 * p], coords[3 * p + 1], coords[3 * p + 2], 0.f);
}

// ---------------- Kernel 1: enc moments + shortcut feat moments (pipelined gathers)
__global__ __launch_bounds__(256) void k_stats(
    const float4* __restrict__ c4, const float* __restrict__ feats,
    const int* __restrict__ idx, float* __restrict__ ws) {
    const int tid = threadIdx.x;
    const int p = blockIdx.x * 256 + tid;
    const int b = p >> 16;
    const int n = p & (NN - 1);

    // shortcut feature moments first (retire registers before nbr loop)
    {
        float accf[44];
        float f[8];
#pragma unroll
        for (int i = 0; i < 8; i++) f[i] = feats[(b * 8 + i) * NN + n];
#pragma unroll
        for (int i = 0; i < 8; i++) accf[i] = f[i];
        int t2 = 8;
#pragma unroll
        for (int i = 0; i < 8; i++)
#pragma unroll
            for (int j = i; j < 8; j++) accf[t2++] = f[i] * f[j];
        blockReduceAtomic<44>(accf, ws + WS_SC_M);
    }

    const int boff = b << 16;
    const float4 me = c4[p];
    const int4* ip = (const int4*)idx + p * 4;
    float sn0 = 0.f, sn1 = 0.f, sn2 = 0.f;
    float m00 = 0.f, m01 = 0.f, m02 = 0.f, m11 = 0.f, m12 = 0.f, m22 = 0.f;

    auto proc = [&](const float4 nn) {
        sn0 += nn.x; sn1 += nn.y; sn2 += nn.z;
        m00 += nn.x * nn.x; m01 += nn.x * nn.y; m02 += nn.x * nn.z;
        m11 += nn.y * nn.y; m12 += nn.y * nn.z; m22 += nn.z * nn.z;
    };

    int4 v = ip[0];
    float4 n0 = c4[boff + v.x], n1 = c4[boff + v.y], n2 = c4[boff + v.z], n3 = c4[boff + v.w];
#pragma unroll 1
    for (int q = 0; q < 3; q++) {
        const int4 vn = ip[q + 1];
        const float4 t0 = c4[boff + vn.x], t1 = c4[boff + vn.y],
                     t2 = c4[boff + vn.z], t3 = c4[boff + vn.w];
        proc(n0); proc(n1); proc(n2); proc(n3);
        n0 = t0; n1 = t1; n2 = t2; n3 = t3;
    }
    proc(n0); proc(n1); proc(n2); proc(n3);

    float acc[27];
    acc[0] = 16.f * me.x; acc[1] = 16.f * me.y; acc[2] = 16.f * me.z;
    acc[3] = sn0; acc[4] = sn1; acc[5] = sn2;
    acc[6] = 16.f * me.x * me.x; acc[7] = 16.f * me.x * me.y; acc[8] = 16.f * me.x * me.z;
    acc[9] = 16.f * me.y * me.y; acc[10] = 16.f * me.y * me.z; acc[11] = 16.f * me.z * me.z;
    acc[12] = me.x * sn0; acc[13] = me.x * sn1; acc[14] = me.x * sn2;
    acc[15] = me.y * sn0; acc[16] = me.y * sn1; acc[17] = me.y * sn2;
    acc[18] = me.z * sn0; acc[19] = me.z * sn1; acc[20] = me.z * sn2;
    acc[21] = m00; acc[22] = m01; acc[23] = m02;
    acc[24] = m11; acc[25] = m12; acc[26] = m22;
    blockReduceAtomic<27>(acc, ws + WS_ENC_M);
}

// ---------------- Kernel 2: mlp1 + lse1 + pool1 -> y2 (pre-BN), bn_p1 raw sums
__global__ __launch_bounds__(256) void k_pool1(
    const float4* __restrict__ c4, const float* __restrict__ feats,
    const int* __restrict__ idx,
    const float* __restrict__ w1, const float* __restrict__ b1,
    const float* __restrict__ lse1_w, const float* __restrict__ lse1_b,
    const float* __restrict__ lse1_g, const float* __restrict__ lse1_bt,
    const float* __restrict__ p1_sw, const float* __restrict__ p1_w,
    const float* __restrict__ p1_b, float* __restrict__ ws) {
    __shared__ float an[24], dc3[24], dcon[8], sws[64], pws[128], pbs[8], w1s[64], b1s[8];
    const int tid = threadIdx.x;
    if (tid < 8) {
        const int c = tid;
        const float* w = lse1_w + c * 10;
        float sc, sh;
        bn_from_enc(ws + WS_ENC_M, w, lse1_b[c], lse1_g[c], lse1_bt[c], sc, sh);
#pragma unroll
        for (int i = 0; i < 3; i++) {
            an[c * 3 + i] = sc * (w[3 + i] - w[6 + i]);
            dc3[c * 3 + i] = sc * (w[i] + w[6 + i]);
        }
        dcon[c] = sc * (lse1_b[c] + w[9]) + sh;
        b1s[c] = b1[c]; pbs[c] = p1_b[c];
    }
    if (tid < 64) {
        w1s[tid] = w1[tid];
        sws[tid] = p1_sw[(tid >> 3) * 16 + (tid & 7)] * LOG2E;  // 8x8 block, exp2-folded
    }
    if (tid < 128) pws[tid] = p1_w[tid];
    __syncthreads();

    const int p = blockIdx.x * 256 + tid;
    const int b = p >> 16;
    const int n = p & (NN - 1);
    const int boff = b << 16;
    const float4 me = c4[p];
    float d[8];
#pragma unroll
    for (int c = 0; c < 8; c++)
        d[c] = dc3[c * 3] * me.x + dc3[c * 3 + 1] * me.y + dc3[c * 3 + 2] * me.z + dcon[c];
    const int4* ip = (const int4*)idx + p * 4;
    float l[8] = {}, ac[8] = {};

    auto proc = [&](const float4 nn) {
        float h[8];
#pragma unroll
        for (int c = 0; c < 8; c++) {
            float y = an[c * 3] * nn.x + an[c * 3 + 1] * nn.y + an[c * 3 + 2] * nn.z + d[c];
            h[c] = y > 0.f ? y : 0.f;
        }
#pragma unroll
        for (int o = 0; o < 8; o++) {
            float s = 0.f;
#pragma unroll
            for (int i = 0; i < 8; i++) s += h[i] * sws[o * 8 + i];
            float e2 = exp2f(s);  // k-const part of score cancels in softmax
            l[o] += e2; ac[o] += e2 * h[o];
        }
    };

    int4 v = ip[0];
    float4 n0 = c4[boff + v.x], n1 = c4[boff + v.y], n2 = c4[boff + v.z], n3 = c4[boff + v.w];
#pragma unroll 1
    for (int q = 0; q < 3; q++) {
        const int4 vn = ip[q + 1];
        const float4 t0 = c4[boff + vn.x], t1 = c4[boff + vn.y],
                     t2 = c4[boff + vn.z], t3 = c4[boff + vn.w];
        proc(n0); proc(n1); proc(n2); proc(n3);
        n0 = t0; n1 = t1; n2 = t2; n3 = t3;
    }
    proc(n0); proc(n1); proc(n2); proc(n3);

    // epilogue: mlp1 (broadcast channels pool to themselves), pool1 conv
    float f[8];
#pragma unroll
    for (int i = 0; i < 8; i++) f[i] = feats[(b * 8 + i) * NN + n];
    float agg[16];
#pragma unroll
    for (int o = 0; o < 8; o++) agg[o] = ac[o] * __builtin_amdgcn_rcpf(l[o]);
#pragma unroll
    for (int jq = 0; jq < 8; jq++) {
        float y = b1s[jq];
#pragma unroll
        for (int i = 0; i < 8; i++) y += f[i] * w1s[jq * 8 + i];
        agg[8 + jq] = y > 0.f ? y : 0.2f * y;  // LeakyReLU(0.2)
    }
    float st[16];
#pragma unroll
    for (int c = 0; c < 8; c++) {
        float y = pbs[c];
#pragma unroll
        for (int o = 0; o < 16; o++) y += agg[o] * pws[c * 16 + o];
        ws[WS_Y2 + c * NP + p] = y;
        st[c] = y; st[8 + c] = y * y;
    }
    blockReduceAtomic<16>(st, ws + WS_S_Y2);
}

// ---------------- Kernel 3: bn_p1+relu -> x2, lse2 + pool2 -> y4 (pre-BN), bn_p2 raw sums
__global__ __launch_bounds__(256) void k_pool2(
    const float4* __restrict__ c4, const int* __restrict__ idx,
    const float* __restrict__ lse2_w, const float* __restrict__ lse2_b,
    const float* __restrict__ lse2_g, const float* __restrict__ lse2_bt,
    const float* __restrict__ p1_g, const float* __restrict__ p1_bt,
    const float* __restrict__ p2_sw, const float* __restrict__ p2_w,
    const float* __restrict__ p2_b, float* __restrict__ ws) {
    __shared__ float an[24], dc3[24], dcon[8], p1sc[8], p1sh[8], sws[64], pws[256], pbs[16];
    const int tid = threadIdx.x;
    if (tid < 8) {
        const int c = tid;
        const float* w = lse2_w + c * 10;
        float sc, sh;
        bn_from_enc(ws + WS_ENC_M, w, lse2_b[c], lse2_g[c], lse2_bt[c], sc, sh);
#pragma unroll
        for (int i = 0; i < 3; i++) {
            an[c * 3 + i] = sc * (w[3 + i] - w[6 + i]);
            dc3[c * 3 + i] = sc * (w[i] + w[6 + i]);
        }
        dcon[c] = sc * (lse2_b[c] + w[9]) + sh;
    } else if (tid < 16) {  // bn_p1 from raw sums
        const int c = tid - 8;
        const float cP = 1.f / (float)NP;
        float m = ws[WS_S_Y2 + c] * cP, vv = ws[WS_SS_Y2 + c] * cP - m * m;
        float sc = p1_g[c] * rsqrtf(vv + BN_EPS);
        p1sc[c] = sc; p1sh[c] = p1_bt[c] - m * sc;
    }
    if (tid < 64) sws[tid] = p2_sw[(tid >> 3) * 16 + (tid & 7)] * LOG2E;
    if (tid < 256) pws[tid] = p2_w[tid];
    if (tid < 16) pbs[tid] = p2_b[tid];
    __syncthreads();

    const int p = blockIdx.x * 256 + tid;
    const int boff = (p >> 16) << 16;
    const float4 me = c4[p];
    float d[8];
#pragma unroll
    for (int c = 0; c < 8; c++)
        d[c] = dc3[c * 3] * me.x + dc3[c * 3 + 1] * me.y + dc3[c * 3 + 2] * me.z + dcon[c];
    const int4* ip = (const int4*)idx + p * 4;
    float l[8] = {}, ac[8] = {};

    auto proc = [&](const float4 nn) {
        float h[8];
#pragma unroll
        for (int c = 0; c < 8; c++) {
            float y = an[c * 3] * nn.x + an[c * 3 + 1] * nn.y + an[c * 3 + 2] * nn.z + d[c];
            h[c] = y > 0.f ? y : 0.f;
        }
#pragma unroll
        for (int o = 0; o < 8; o++) {
            float s = 0.f;
#pragma unroll
            for (int i = 0; i < 8; i++) s += h[i] * sws[o * 8 + i];
            float e2 = exp2f(s);
            l[o] += e2; ac[o] += e2 * h[o];
        }
    };

    int4 v = ip[0];
    float4 n0 = c4[boff + v.x], n1 = c4[boff + v.y], n2 = c4[boff + v.z], n3 = c4[boff + v.w];
#pragma unroll 1
    for (int q = 0; q < 3; q++) {
        const int4 vn = ip[q + 1];
        const float4 t0 = c4[boff + vn.x], t1 = c4[boff + vn.y],
                     t2 = c4[boff + vn.z], t3 = c4[boff + vn.w];
        proc(n0); proc(n1); proc(n2); proc(n3);
        n0 = t0; n1 = t1; n2 = t2; n3 = t3;
    }
    proc(n0); proc(n1); proc(n2); proc(n3);

    float agg[16];
#pragma unroll
    for (int o = 0; o < 8; o++) agg[o] = ac[o] * __builtin_amdgcn_rcpf(l[o]);
#pragma unroll
    for (int c = 0; c < 8; c++) {
        float y = ws[WS_Y2 + c * NP + p] * p1sc[c] + p1sh[c];
        agg[8 + c] = y > 0.f ? y : 0.f;
    }
    float st[32];
#pragma unroll
    for (int c = 0; c < 16; c++) {
        float y = pbs[c];
#pragma unroll
        for (int o = 0; o < 16; o++) y += agg[o] * pws[c * 16 + o];
        ws[WS_Y4 + c * NP + p] = y;
        st[c] = y; st[16 + c] = y * y;
    }
    blockReduceAtomic<32>(st, ws + WS_S_Y4);
}

// ---------------- Kernel 4: x4 = relu(bn(y4)); out = leaky(w2@x4 + b2 + bn(sc_w@feats))
__global__ __launch_bounds__(256) void k_final(
    const float* __restrict__ feats, const float* __restrict__ w2,
    const float* __restrict__ b2, const float* __restrict__ sc_w,
    const float* __restrict__ sc_b, const float* __restrict__ p2_g,
    const float* __restrict__ p2_bt, const float* __restrict__ sc_g,
    const float* __restrict__ sc_bt, const float* __restrict__ ws,
    float* __restrict__ out) {
    __shared__ float w2s[512], b2s[32], scws[256], scbs[32],
        p2sc[16], p2sh[16], scsc[32], scsh[32];
    const int tid = threadIdx.x;
    for (int i = tid; i < 512; i += 256) w2s[i] = w2[i];
    if (tid < 256) scws[tid] = sc_w[tid];
    if (tid < 32) {
        b2s[tid] = b2[tid]; scbs[tid] = sc_b[tid];
        const int c = tid;
        const float* w = sc_w + c * 8;
        const float* S = ws + WS_SC_M;
        float lin = 0.f;
#pragma unroll
        for (int i = 0; i < 8; i++) lin += w[i] * S[i];
        float quad = 0.f;
        int t2 = 0;
#pragma unroll
        for (int i = 0; i < 8; i++)
#pragma unroll
            for (int j = i; j < 8; j++) {
                const float mm = S[8 + t2++];
                quad += (i == j ? 1.f : 2.f) * w[i] * w[j] * mm;
            }
        const float cnt = (float)NP;
        const float bb = sc_b[c];
        const float sum = lin + cnt * bb;
        const float ss = quad + 2.f * bb * lin + cnt * bb * bb;
        const float m = sum / cnt, vv = ss / cnt - m * m;
        const float sc = sc_g[c] * rsqrtf(vv + BN_EPS);
        scsc[c] = sc; scsh[c] = sc_bt[c] - m * sc;
    }
    if (tid < 16) {
        const int c = tid;
        const float cP = 1.f / (float)NP;
        float m = ws[WS_S_Y4 + c] * cP, vv = ws[WS_SS_Y4 + c] * cP - m * m;
        float sc = p2_g[c] * rsqrtf(vv + BN_EPS);
        p2sc[c] = sc; p2sh[c] = p2_bt[c] - m * sc;
    }
    __syncthreads();

    const int p = blockIdx.x * 256 + tid;
    const int b = p >> 16;
    const int n = p & (NN - 1);
    float x4[16];
#pragma unroll
    for (int c = 0; c < 16; c++) {
        float y = ws[WS_Y4 + c * NP + p] * p2sc[c] + p2sh[c];
        x4[c] = y > 0.f ? y : 0.f;
    }
    float f[8];
#pragma unroll
    for (int i = 0; i < 8; i++) f[i] = feats[(b * 8 + i) * NN + n];
#pragma unroll
    for (int c = 0; c < 32; c++) {
        float s = scbs[c];
#pragma unroll
        for (int i = 0; i < 8; i++) s += f[i] * scws[c * 8 + i];
        s = s * scsc[c] + scsh[c];  // bn, no activation
        float m = b2s[c];
#pragma unroll
        for (int o = 0; o < 16; o++) m += x4[o] * w2s[c * 16 + o];
        float vv = m + s;
        out[(b * 32 + c) * NN + n] = vv > 0.f ? vv : 0.01f * vv;  // LeakyReLU(0.01)
    }
}

extern "C" void kernel_launch(void* const* d_in, const int* in_sizes, int n_in,
                              void* d_out, int out_size, void* d_ws, size_t ws_size,
                              hipStream_t stream) {
    (void)in_sizes; (void)n_in; (void)out_size; (void)ws_size;
    const float* coords = (const float*)d_in[0];
    const float* features = (const float*)d_in[1];
    const int* idx = (const int*)d_in[2];
    const float* w1 = (const float*)d_in[3];
    const float* b1 = (const float*)d_in[4];
    const float* lse1_w = (const float*)d_in[5];
    const float* lse1_b = (const float*)d_in[6];
    const float* lse1_g = (const float*)d_in[7];
    const float* lse1_bt = (const float*)d_in[8];
    const float* p1_sw = (const float*)d_in[9];
    const float* p1_w = (const float*)d_in[10];
    const float* p1_b = (const float*)d_in[11];
    const float* p1_g = (const float*)d_in[12];
    const float* p1_bt = (const float*)d_in[13];
    const float* lse2_w = (const float*)d_in[14];
    const float* lse2_b = (const float*)d_in[15];
    const float* lse2_g = (const float*)d_in[16];
    const float* lse2_bt = (const float*)d_in[17];
    const float* p2_sw = (const float*)d_in[18];
    const float* p2_w = (const float*)d_in[19];
    const float* p2_b = (const float*)d_in[20];
    const float* p2_g = (const float*)d_in[21];
    const float* p2_bt = (const float*)d_in[22];
    const float* w2 = (const float*)d_in[23];
    const float* b2 = (const float*)d_in[24];
    const float* sc_w = (const float*)d_in[25];
    const float* sc_b = (const float*)d_in[26];
    const float* sc_g = (const float*)d_in[27];
    const float* sc_bt = (const float*)d_in[28];
    float* ws = (float*)d_ws;
    float* out = (float*)d_out;
    float4* c4 = (float4*)(ws + WS_C4);

    const int NBLK = NP / 256;
    hipMemsetAsync(ws, 0, 144 * sizeof(float), stream);
    k_prep<<<NBLK, 256, 0, stream>>>(coords, c4);
    k_stats<<<NBLK, 256, 0, stream>>>(c4, features, idx, ws);
    k_pool1<<<NBLK, 256, 0, stream>>>(c4, features, idx, w1, b1, lse1_w, lse1_b,
                                      lse1_g, lse1_bt, p1_sw, p1_w, p1_b, ws);
    k_pool2<<<NBLK, 256, 0, stream>>>(c4, idx, lse2_w, lse2_b, lse2_g, lse2_bt,
                                      p1_g, p1_bt, p2_sw, p2_w, p2_b, ws);
    k_final<<<NBLK, 256, 0, stream>>>(features, w2, b2, sc_w, sc_b, p2_g, p2_bt,
                                      sc_g, sc_bt, ws, out);
}

// Round 11
// 332.741 us; speedup vs baseline: 1.1951x; 1.0502x over previous
//
#include <hip/hip_runtime.h>

#define NB 4
#define NN 65536
#define NK 16
#define NP (NB * NN)   // 262144 points
#define BN_EPS 1e-6f
#define LOG2E 1.44269504088896f

// ---- workspace layout (floats) ----
#define WS_ENC_M   0    // 27 floats: enc moments basis [c,n,1]
#define WS_SC_M    32   // S_f[8] @32, M_ff upper-tri 36 @40  (44 floats)
#define WS_S_Y2    96   // 8  pool1 conv sum
#define WS_SS_Y2   104  // 8
#define WS_S_Y4    112  // 16 pool2 conv sum
#define WS_SS_Y4   128  // 16 -> raw stats end at 144
#define WS_Y2      1024               // NP*8  floats (8 MB), channel-major
#define WS_Y4      (1024 + NP * 8)    // NP*16 floats (16 MB); pool1 writes partial, pool2e finalizes
#define WS_C4      (1024 + NP * 24)   // NP*4  floats (4 MB) packed coords float4

// entry+exit barriers REQUIRED (R5 lesson: LDS overlay races at high occupancy)
template <int NCH>
__device__ inline void blockReduceAtomic(float (&v)[NCH], float* __restrict__ dst) {
    __shared__ float red[4][NCH];
    const int lane = threadIdx.x & 63;
    const int wv = threadIdx.x >> 6;
    __syncthreads();
#pragma unroll
    for (int c = 0; c < NCH; c++) {
        float x = v[c];
#pragma unroll
        for (int off = 32; off > 0; off >>= 1) x += __shfl_xor(x, off, 64);
        if (lane == 0) red[wv][c] = x;
    }
    __syncthreads();
    for (int c = threadIdx.x; c < NCH; c += 256)
        atomicAdd(dst + c, red[0][c] + red[1][c] + red[2][c] + red[3][c]);
    __syncthreads();
}

// bn scale/shift for an lse conv channel from enc moments. w points at 10 weights.
__device__ inline void bn_from_enc(const float* __restrict__ M, const float* __restrict__ w,
                                   float b, float g, float bt, float& sc, float& sh) {
    float u[6];
    u[0] = w[0] + w[6]; u[1] = w[1] + w[7]; u[2] = w[2] + w[8];
    u[3] = w[3] - w[6]; u[4] = w[4] - w[7]; u[5] = w[5] - w[8];
    const float beta = b + w[9];
    float lin = 0.f;
#pragma unroll
    for (int i = 0; i < 6; i++) lin += u[i] * M[i];
    float quad = u[0] * u[0] * M[6] + 2.f * u[0] * u[1] * M[7] + 2.f * u[0] * u[2] * M[8]
               + u[1] * u[1] * M[9] + 2.f * u[1] * u[2] * M[10] + u[2] * u[2] * M[11];
#pragma unroll
    for (int i = 0; i < 3; i++)
#pragma unroll
        for (int j = 0; j < 3; j++) quad += 2.f * u[i] * u[3 + j] * M[12 + i * 3 + j];
    quad += u[3] * u[3] * M[21] + 2.f * u[3] * u[4] * M[22] + 2.f * u[3] * u[5] * M[23]
          + u[4] * u[4] * M[24] + 2.f * u[4] * u[5] * M[25] + u[5] * u[5] * M[26];
    const float cnt = (float)NP * (float)NK;
    const float sum = lin + cnt * beta;
    const float ss = quad + 2.f * beta * lin + cnt * beta * beta;
    const float m = sum / cnt, v = ss / cnt - m * m;
    sc = g * rsqrtf(v + BN_EPS);
    sh = bt - m * sc;
}

// ---------------- Kernel 1: pack c4 + enc moments + shortcut feat moments
__global__ __launch_bounds__(256) void k_stats(
    const float* __restrict__ coords, const float* __restrict__ feats,
    const int* __restrict__ idx, float4* __restrict__ c4, float* __restrict__ ws) {
    const int tid = threadIdx.x;
    const int p = blockIdx.x * 256 + tid;
    const int b = p >> 16;
    const int n = p & (NN - 1);

    // shortcut feature moments first (retire registers before nbr loop)
    {
        float accf[44];
        float f[8];
#pragma unroll
        for (int i = 0; i < 8; i++) f[i] = feats[(b * 8 + i) * NN + n];
#pragma unroll
        for (int i = 0; i < 8; i++) accf[i] = f[i];
        int t2 = 8;
#pragma unroll
        for (int i = 0; i < 8; i++)
#pragma unroll
            for (int j = i; j < 8; j++) accf[t2++] = f[i] * f[j];
        blockReduceAtomic<44>(accf, ws + WS_SC_M);
    }

    const float cx = coords[3 * p], cy = coords[3 * p + 1], cz = coords[3 * p + 2];
    c4[p] = make_float4(cx, cy, cz, 0.f);
    const float* cb = coords + b * NN * 3;
    const int4* ip = (const int4*)idx + p * 4;
    float sn0 = 0.f, sn1 = 0.f, sn2 = 0.f;
    float m00 = 0.f, m01 = 0.f, m02 = 0.f, m11 = 0.f, m12 = 0.f, m22 = 0.f;

    auto proc = [&](float nx, float ny, float nz) {
        sn0 += nx; sn1 += ny; sn2 += nz;
        m00 += nx * nx; m01 += nx * ny; m02 += nx * nz;
        m11 += ny * ny; m12 += ny * nz; m22 += nz * nz;
    };

    int4 v0 = ip[0];
    float ax[4], ay[4], az[4];
    {
        int jj[4] = {v0.x, v0.y, v0.z, v0.w};
#pragma unroll
        for (int e = 0; e < 4; e++) {
            ax[e] = cb[3 * jj[e]]; ay[e] = cb[3 * jj[e] + 1]; az[e] = cb[3 * jj[e] + 2];
        }
    }
#pragma unroll 1
    for (int q = 0; q < 3; q++) {
        const int4 vn = ip[q + 1];
        int jj[4] = {vn.x, vn.y, vn.z, vn.w};
        float tx[4], ty[4], tz[4];
#pragma unroll
        for (int e = 0; e < 4; e++) {
            tx[e] = cb[3 * jj[e]]; ty[e] = cb[3 * jj[e] + 1]; tz[e] = cb[3 * jj[e] + 2];
        }
#pragma unroll
        for (int e = 0; e < 4; e++) proc(ax[e], ay[e], az[e]);
#pragma unroll
        for (int e = 0; e < 4; e++) { ax[e] = tx[e]; ay[e] = ty[e]; az[e] = tz[e]; }
    }
#pragma unroll
    for (int e = 0; e < 4; e++) proc(ax[e], ay[e], az[e]);

    float acc[27];
    acc[0] = 16.f * cx; acc[1] = 16.f * cy; acc[2] = 16.f * cz;
    acc[3] = sn0; acc[4] = sn1; acc[5] = sn2;
    acc[6] = 16.f * cx * cx; acc[7] = 16.f * cx * cy; acc[8] = 16.f * cx * cz;
    acc[9] = 16.f * cy * cy; acc[10] = 16.f * cy * cz; acc[11] = 16.f * cz * cz;
    acc[12] = cx * sn0; acc[13] = cx * sn1; acc[14] = cx * sn2;
    acc[15] = cy * sn0; acc[16] = cy * sn1; acc[17] = cy * sn2;
    acc[18] = cz * sn0; acc[19] = cz * sn1; acc[20] = cz * sn2;
    acc[21] = m00; acc[22] = m01; acc[23] = m02;
    acc[24] = m11; acc[25] = m12; acc[26] = m22;
    blockReduceAtomic<27>(acc, ws + WS_ENC_M);
}

// ---------------- Kernel 2: ONE gather pass for BOTH pools.
// pool1: full y2 (lse1 softmax-pool + mlp1, conv) -> Y2 + stats
// pool2: k-dependent part only (lse2 softmax-pool of h2) -> partial y4 into Y4
__global__ __launch_bounds__(256) void k_pool1(
    const float4* __restrict__ c4, const float* __restrict__ feats,
    const int* __restrict__ idx,
    const float* __restrict__ w1, const float* __restrict__ b1,
    const float* __restrict__ lse1_w, const float* __restrict__ lse1_b,
    const float* __restrict__ lse1_g, const float* __restrict__ lse1_bt,
    const float* __restrict__ lse2_w, const float* __restrict__ lse2_b,
    const float* __restrict__ lse2_g, const float* __restrict__ lse2_bt,
    const float* __restrict__ p1_sw, const float* __restrict__ p1_w,
    const float* __restrict__ p1_b,
    const float* __restrict__ p2_sw, const float* __restrict__ p2_w,
    const float* __restrict__ p2_b, float* __restrict__ ws) {
    __shared__ float an1[24], dcA[24], dkA[8], an2[24], dcB[24], dkB[8],
        sws1[64], sws2[64], pws1[128], pws2[256], pbs1[8], pbs2[16], w1s[64], b1s[8];
    const int tid = threadIdx.x;
    if (tid < 8) {
        const int c = tid;
        {
            const float* w = lse1_w + c * 10;
            float sc, sh;
            bn_from_enc(ws + WS_ENC_M, w, lse1_b[c], lse1_g[c], lse1_bt[c], sc, sh);
#pragma unroll
            for (int i = 0; i < 3; i++) {
                an1[c * 3 + i] = sc * (w[3 + i] - w[6 + i]);
                dcA[c * 3 + i] = sc * (w[i] + w[6 + i]);
            }
            dkA[c] = sc * (lse1_b[c] + w[9]) + sh;
        }
        {
            const float* w = lse2_w + c * 10;
            float sc, sh;
            bn_from_enc(ws + WS_ENC_M, w, lse2_b[c], lse2_g[c], lse2_bt[c], sc, sh);
#pragma unroll
            for (int i = 0; i < 3; i++) {
                an2[c * 3 + i] = sc * (w[3 + i] - w[6 + i]);
                dcB[c * 3 + i] = sc * (w[i] + w[6 + i]);
            }
            dkB[c] = sc * (lse2_b[c] + w[9]) + sh;
        }
        b1s[c] = b1[c]; pbs1[c] = p1_b[c];
    }
    if (tid < 16) pbs2[tid] = p2_b[tid];
    if (tid < 64) {
        w1s[tid] = w1[tid];
        sws1[tid] = p1_sw[(tid >> 3) * 16 + (tid & 7)] * LOG2E;  // 8x8 block, exp2-folded
        sws2[tid] = p2_sw[(tid >> 3) * 16 + (tid & 7)] * LOG2E;
    }
    if (tid < 128) pws1[tid] = p1_w[tid];
    if (tid < 256) pws2[tid] = p2_w[tid];
    __syncthreads();

    const int p = blockIdx.x * 256 + tid;
    const int b = p >> 16;
    const int n = p & (NN - 1);
    const int boff = b << 16;
    const float4 me = c4[p];
    float d1[8], d2[8];
#pragma unroll
    for (int c = 0; c < 8; c++) {
        d1[c] = dcA[c * 3] * me.x + dcA[c * 3 + 1] * me.y + dcA[c * 3 + 2] * me.z + dkA[c];
        d2[c] = dcB[c * 3] * me.x + dcB[c * 3 + 1] * me.y + dcB[c * 3 + 2] * me.z + dkB[c];
    }
    const int4* ip = (const int4*)idx + p * 4;
    float l1[8] = {}, a1[8] = {}, l2[8] = {}, a2[8] = {};

    auto proc = [&](const float4 nn) {
        float h[8];
#pragma unroll
        for (int c = 0; c < 8; c++) {
            float y = an1[c * 3] * nn.x + an1[c * 3 + 1] * nn.y + an1[c * 3 + 2] * nn.z + d1[c];
            h[c] = y > 0.f ? y : 0.f;
        }
#pragma unroll
        for (int o = 0; o < 8; o++) {
            float s = 0.f;
#pragma unroll
            for (int i = 0; i < 8; i++) s += h[i] * sws1[o * 8 + i];
            float e2 = exp2f(s);  // k-const part of score cancels in softmax
            l1[o] += e2; a1[o] += e2 * h[o];
        }
#pragma unroll
        for (int c = 0; c < 8; c++) {
            float y = an2[c * 3] * nn.x + an2[c * 3 + 1] * nn.y + an2[c * 3 + 2] * nn.z + d2[c];
            h[c] = y > 0.f ? y : 0.f;
        }
#pragma unroll
        for (int o = 0; o < 8; o++) {
            float s = 0.f;
#pragma unroll
            for (int i = 0; i < 8; i++) s += h[i] * sws2[o * 8 + i];
            float e2 = exp2f(s);
            l2[o] += e2; a2[o] += e2 * h[o];
        }
    };

    int4 v = ip[0];
    float4 n0 = c4[boff + v.x], n1 = c4[boff + v.y], n2 = c4[boff + v.z], n3 = c4[boff + v.w];
#pragma unroll 1
    for (int q = 0; q < 3; q++) {
        const int4 vn = ip[q + 1];
        const float4 t0 = c4[boff + vn.x], t1 = c4[boff + vn.y],
                     t2 = c4[boff + vn.z], t3 = c4[boff + vn.w];
        proc(n0); proc(n1); proc(n2); proc(n3);
        n0 = t0; n1 = t1; n2 = t2; n3 = t3;
    }
    proc(n0); proc(n1); proc(n2); proc(n3);

    // epilogue A: pool1 full conv -> Y2 + stats
    float f[8];
#pragma unroll
    for (int i = 0; i < 8; i++) f[i] = feats[(b * 8 + i) * NN + n];
    float agg[16];
#pragma unroll
    for (int o = 0; o < 8; o++) agg[o] = a1[o] * __builtin_amdgcn_rcpf(l1[o]);
#pragma unroll
    for (int jq = 0; jq < 8; jq++) {
        float y = b1s[jq];
#pragma unroll
        for (int i = 0; i < 8; i++) y += f[i] * w1s[jq * 8 + i];
        agg[8 + jq] = y > 0.f ? y : 0.2f * y;  // LeakyReLU(0.2)
    }
    float st[16];
#pragma unroll
    for (int c = 0; c < 8; c++) {
        float y = pbs1[c];
#pragma unroll
        for (int o = 0; o < 16; o++) y += agg[o] * pws1[c * 16 + o];
        ws[WS_Y2 + c * NP + p] = y;
        st[c] = y; st[8 + c] = y * y;
    }
    // epilogue B: pool2 partial conv (k-dependent half) -> Y4
    float g2[8];
#pragma unroll
    for (int o = 0; o < 8; o++) g2[o] = a2[o] * __builtin_amdgcn_rcpf(l2[o]);
#pragma unroll
    for (int c = 0; c < 16; c++) {
        float y = pbs2[c];
#pragma unroll
        for (int o = 0; o < 8; o++) y += g2[o] * pws2[c * 16 + o];
        ws[WS_Y4 + c * NP + p] = y;
    }
    blockReduceAtomic<16>(st, ws + WS_S_Y2);
}

// ---------------- Kernel 3 (elementwise, no gathers): finish y4, bn_p2 raw sums
__global__ __launch_bounds__(256) void k_pool2e(
    const float* __restrict__ p1_g, const float* __restrict__ p1_bt,
    const float* __restrict__ p2_w, float* __restrict__ ws) {
    __shared__ float p1sc[8], p1sh[8], pwsb[128];
    const int tid = threadIdx.x;
    if (tid < 8) {  // bn_p1 from raw sums
        const int c = tid;
        const float cP = 1.f / (float)NP;
        float m = ws[WS_S_Y2 + c] * cP, vv = ws[WS_SS_Y2 + c] * cP - m * m;
        float sc = p1_g[c] * rsqrtf(vv + BN_EPS);
        p1sc[c] = sc; p1sh[c] = p1_bt[c] - m * sc;
    }
    if (tid < 128) pwsb[tid] = p2_w[(tid >> 3) * 16 + 8 + (tid & 7)];  // W2[c][8+o]
    __syncthreads();

    const int p = blockIdx.x * 256 + tid;
    float x2[8];
#pragma unroll
    for (int c = 0; c < 8; c++) {
        float y = ws[WS_Y2 + c * NP + p] * p1sc[c] + p1sh[c];
        x2[c] = y > 0.f ? y : 0.f;
    }
    float st[32];
#pragma unroll
    for (int c = 0; c < 16; c++) {
        float y = ws[WS_Y4 + c * NP + p];
#pragma unroll
        for (int o = 0; o < 8; o++) y += x2[o] * pwsb[c * 8 + o];
        ws[WS_Y4 + c * NP + p] = y;
        st[c] = y; st[16 + c] = y * y;
    }
    blockReduceAtomic<32>(st, ws + WS_S_Y4);
}

// ---------------- Kernel 4: x4 = relu(bn(y4)); out = leaky(w2@x4 + b2 + bn(sc_w@feats))
__global__ __launch_bounds__(256) void k_final(
    const float* __restrict__ feats, const float* __restrict__ w2,
    const float* __restrict__ b2, const float* __restrict__ sc_w,
    const float* __restrict__ sc_b, const float* __restrict__ p2_g,
    const float* __restrict__ p2_bt, const float* __restrict__ sc_g,
    const float* __restrict__ sc_bt, const float* __restrict__ ws,
    float* __restrict__ out) {
    __shared__ float w2s[512], b2s[32], scws[256], scbs[32],
        p2sc[16], p2sh[16], scsc[32], scsh[32];
    const int tid = threadIdx.x;
    for (int i = tid; i < 512; i += 256) w2s[i] = w2[i];
    if (tid < 256) scws[tid] = sc_w[tid];
    if (tid < 32) {
        b2s[tid] = b2[tid]; scbs[tid] = sc_b[tid];
        const int c = tid;
        const float* w = sc_w + c * 8;
        const float* S = ws + WS_SC_M;
        float lin = 0.f;
#pragma unroll
        for (int i = 0; i < 8; i++) lin += w[i] * S[i];
        float quad = 0.f;
        int t2 = 0;
#pragma unroll
        for (int i = 0; i < 8; i++)
#pragma unroll
            for (int j = i; j < 8; j++) {
                const float mm = S[8 + t2++];
                quad += (i == j ? 1.f : 2.f) * w[i] * w[j] * mm;
            }
        const float cnt = (float)NP;
        const float bb = sc_b[c];
        const float sum = lin + cnt * bb;
        const float ss = quad + 2.f * bb * lin + cnt * bb * bb;
        const float m = sum / cnt, vv = ss / cnt - m * m;
        const float sc = sc_g[c] * rsqrtf(vv + BN_EPS);
        scsc[c] = sc; scsh[c] = sc_bt[c] - m * sc;
    }
    if (tid < 16) {
        const int c = tid;
        const float cP = 1.f / (float)NP;
        float m = ws[WS_S_Y4 + c] * cP, vv = ws[WS_SS_Y4 + c] * cP - m * m;
        float sc = p2_g[c] * rsqrtf(vv + BN_EPS);
        p2sc[c] = sc; p2sh[c] = p2_bt[c] - m * sc;
    }
    __syncthreads();

    const int p = blockIdx.x * 256 + tid;
    const int b = p >> 16;
    const int n = p & (NN - 1);
    float x4[16];
#pragma unroll
    for (int c = 0; c < 16; c++) {
        float y = ws[WS_Y4 + c * NP + p] * p2sc[c] + p2sh[c];
        x4[c] = y > 0.f ? y : 0.f;
    }
    float f[8];
#pragma unroll
    for (int i = 0; i < 8; i++) f[i] = feats[(b * 8 + i) * NN + n];
#pragma unroll
    for (int c = 0; c < 32; c++) {
        float s = scbs[c];
#pragma unroll
        for (int i = 0; i < 8; i++) s += f[i] * scws[c * 8 + i];
        s = s * scsc[c] + scsh[c];  // bn, no activation
        float m = b2s[c];
#pragma unroll
        for (int o = 0; o < 16; o++) m += x4[o] * w2s[c * 16 + o];
        float vv = m + s;
        out[(b * 32 + c) * NN + n] = vv > 0.f ? vv : 0.01f * vv;  // LeakyReLU(0.01)
    }
}

extern "C" void kernel_launch(void* const* d_in, const int* in_sizes, int n_in,
                              void* d_out, int out_size, void* d_ws, size_t ws_size,
                              hipStream_t stream) {
    (void)in_sizes; (void)n_in; (void)out_size; (void)ws_size;
    const float* coords = (const float*)d_in[0];
    const float* features = (const float*)d_in[1];
    const int* idx = (const int*)d_in[2];
    const float* w1 = (const float*)d_in[3];
    const float* b1 = (const float*)d_in[4];
    const float* lse1_w = (const float*)d_in[5];
    const float* lse1_b = (const float*)d_in[6];
    const float* lse1_g = (const float*)d_in[7];
    const float* lse1_bt = (const float*)d_in[8];
    const float* p1_sw = (const float*)d_in[9];
    const float* p1_w = (const float*)d_in[10];
    const float* p1_b = (const float*)d_in[11];
    const float* p1_g = (const float*)d_in[12];
    const float* p1_bt = (const float*)d_in[13];
    const float* lse2_w = (const float*)d_in[14];
    const float* lse2_b = (const float*)d_in[15];
    const float* lse2_g = (const float*)d_in[16];
    const float* lse2_bt = (const float*)d_in[17];
    const float* p2_sw = (const float*)d_in[18];
    const float* p2_w = (const float*)d_in[19];
    const float* p2_b = (const float*)d_in[20];
    const float* p2_g = (const float*)d_in[21];
    const float* p2_bt = (const float*)d_in[22];
    const float* w2 = (const float*)d_in[23];
    const float* b2 = (const float*)d_in[24];
    const float* sc_w = (const float*)d_in[25];
    const float* sc_b = (const float*)d_in[26];
    const float* sc_g = (const float*)d_in[27];
    const float* sc_bt = (const float*)d_in[28];
    float* ws = (float*)d_ws;
    float* out = (float*)d_out;
    float4* c4 = (float4*)(ws + WS_C4);

    const int NBLK = NP / 256;
    (void)hipMemsetAsync(ws, 0, 144 * sizeof(float), stream);
    k_stats<<<NBLK, 256, 0, stream>>>(coords, features, idx, c4, ws);
    k_pool1<<<NBLK, 256, 0, stream>>>(c4, features, idx, w1, b1,
                                      lse1_w, lse1_b, lse1_g, lse1_bt,
                                      lse2_w, lse2_b, lse2_g, lse2_bt,
                                      p1_sw, p1_w, p1_b, p2_sw, p2_w, p2_b, ws);
    k_pool2e<<<NBLK, 256, 0, stream>>>(p1_g, p1_bt, p2_w, ws);
    k_final<<<NBLK, 256, 0, stream>>>(features, w2, b2, sc_w, sc_b, p2_g, p2_bt,
                                      sc_g, sc_bt, ws, out);
}